// Round 1
// baseline (337.041 us; speedup 1.0000x reference)
//
#include <hip/hip_runtime.h>

typedef unsigned short u16;
typedef __attribute__((ext_vector_type(8))) short short8;
typedef __attribute__((ext_vector_type(4))) float f32x4;

// f32 -> bf16 round-to-nearest-even (finite values only)
__device__ __forceinline__ u16 f2b(float f) {
  unsigned u = __float_as_uint(f);
  unsigned r = (u + 0x7FFFu + ((u >> 16) & 1u)) >> 16;
  return (u16)r;
}

// ---------------------------------------------------------------------------
// prep: q_in[t,b,:] = (t>0 ? fwd[t-1,b,:] : 0) + (t<T-1 ? bwd[t+1,b,:] : 0), bf16
// ---------------------------------------------------------------------------
__global__ __launch_bounds__(256) void prep_qin(const float* __restrict__ fwd,
                                                const float* __restrict__ bwd,
                                                u16* __restrict__ qin) {
  int gid = blockIdx.x * 256 + threadIdx.x;   // 1,048,576 threads, 4 elems each
  int n = gid >> 8;                           // token row (t*4+b), 0..4095
  int e4 = (gid & 255) << 2;                  // column start
  int t = n >> 2, b = n & 3;
  float4 acc = make_float4(0.f, 0.f, 0.f, 0.f);
  if (t > 0) {
    float4 v = *(const float4*)(fwd + (((t - 1) * 4 + b) << 10) + e4);
    acc.x += v.x; acc.y += v.y; acc.z += v.z; acc.w += v.w;
  }
  if (t < 1023) {
    float4 v = *(const float4*)(bwd + (((t + 1) * 4 + b) << 10) + e4);
    acc.x += v.x; acc.y += v.y; acc.z += v.z; acc.w += v.w;
  }
  ushort4 o; o.x = f2b(acc.x); o.y = f2b(acc.y); o.z = f2b(acc.z); o.w = f2b(acc.w);
  *(ushort4*)(qin + (n << 10) + e4) = o;
}

__global__ __launch_bounds__(256) void cast_bf16(const float* __restrict__ src,
                                                 u16* __restrict__ dst) {
  int gid = blockIdx.x * 256 + threadIdx.x;
  float4 v = *(const float4*)(src + (gid << 2));
  ushort4 o; o.x = f2b(v.x); o.y = f2b(v.y); o.z = f2b(v.z); o.w = f2b(v.w);
  *(ushort4*)(dst + (gid << 2)) = o;
}

// ---------------------------------------------------------------------------
// GEMM: C[m,n] = sum_k A[m,k] * W[n,k] + bias[n]   (A,W bf16; K=N=1024)
// 128x128 tile, 4 waves (2x2 of 64x64), mfma_f32_16x16x32_bf16.
// MODE 0: scatter Q -> (B,H,T,Dh) bf16     MODE 1: scatter K -> (B,H,S,Dh) bf16
// MODE 2: scatter V^T -> (B,H,Dh,S) bf16   MODE 3: f32 row-major [m,n] (d_out)
// ---------------------------------------------------------------------------
template <int MODE>
__global__ __launch_bounds__(256) void gemm_bt(const u16* __restrict__ A,
                                               const u16* __restrict__ W,
                                               const float* __restrict__ bias,
                                               void* __restrict__ outp) {
  __shared__ u16 At[128 * 72];   // +8 pad: 144B row stride (16B aligned, bank-spread)
  __shared__ u16 Wt[128 * 72];
  const int m0 = blockIdx.x << 7, n0 = blockIdx.y << 7;
  const int tid = threadIdx.x;
  const int lane = tid & 63, wid = tid >> 6;
  const int wm = (wid >> 1) << 6, wn = (wid & 1) << 6;
  const int lr = lane & 15, lg = lane >> 4;
  f32x4 acc[4][4] = {};
  for (int k0 = 0; k0 < 1024; k0 += 64) {
#pragma unroll
    for (int it = 0; it < 4; it++) {
      int idx = tid + it * 256;               // 1024 chunks of 16B per tile pair
      int row = idx >> 3, c = (idx & 7) << 3;
      *(uint4*)&At[row * 72 + c] = *(const uint4*)&A[(m0 + row) * 1024 + k0 + c];
      *(uint4*)&Wt[row * 72 + c] = *(const uint4*)&W[(n0 + row) * 1024 + k0 + c];
    }
    __syncthreads();
#pragma unroll
    for (int kk = 0; kk < 64; kk += 32) {
      short8 af[4], bf[4];
#pragma unroll
      for (int i = 0; i < 4; i++) {
        af[i] = *(const short8*)&At[(wm + i * 16 + lr) * 72 + kk + lg * 8];
        bf[i] = *(const short8*)&Wt[(wn + i * 16 + lr) * 72 + kk + lg * 8];
      }
#pragma unroll
      for (int i = 0; i < 4; i++)
#pragma unroll
        for (int j = 0; j < 4; j++)
          acc[i][j] = __builtin_amdgcn_mfma_f32_16x16x32_bf16(af[i], bf[j], acc[i][j], 0, 0, 0);
    }
    __syncthreads();
  }
  // epilogue: D row = lg*4+r, col = lr (verified gfx950 C/D layout)
#pragma unroll
  for (int i = 0; i < 4; i++) {
#pragma unroll
    for (int j = 0; j < 4; j++) {
      int n = n0 + wn + j * 16 + lr;
      float bv = bias[n];
#pragma unroll
      for (int r = 0; r < 4; r++) {
        int m = m0 + wm + i * 16 + lg * 4 + r;
        float v = acc[i][j][r] + bv;
        if (MODE == 3) {
          ((float*)outp)[m * 1024 + n] = v;
        } else {
          int tb = m & 3, ts = m >> 2, h = n >> 6, d = n & 63;
          u16* ob = (u16*)outp;
          if (MODE == 0) ob[((tb * 16 + h) * 1024 + ts) * 64 + d] = f2b(v);
          if (MODE == 1) ob[((tb * 16 + h) * 2048 + ts) * 64 + d] = f2b(v);
          if (MODE == 2) ob[((tb * 16 + h) * 64 + d) * 2048 + ts] = f2b(v);
        }
      }
    }
  }
}

// ---------------------------------------------------------------------------
// Flash attention: 1 block = (b, h, 64 q-rows). 4 waves x 16-row strips.
// 17 key-tiles of 64 (mask band [t0+63, t0+1023] skipped structurally).
// Writes attn context (bf16, (T,B,E)) + per-row softmax stats (m, 1/l).
// ---------------------------------------------------------------------------
__global__ __launch_bounds__(256) void attn_fwd(const u16* __restrict__ qb,
                                                const u16* __restrict__ kb,
                                                const u16* __restrict__ vtb,
                                                u16* __restrict__ attn_bf,
                                                float* __restrict__ st_m,
                                                float* __restrict__ st_il) {
  __shared__ u16 Kt[64 * 72];
  __shared__ u16 Vt[64 * 72];
  __shared__ u16 Pt[4][16 * 72];
  const int blk = blockIdx.x;
  const int t0 = (blk & 15) << 6;
  const int h = (blk >> 4) & 15;
  const int b = blk >> 8;
  const int tid = threadIdx.x, lane = tid & 63, w = tid >> 6;
  const int lr = lane & 15, lg = lane >> 4;
  const int bh = b * 16 + h;
  const u16* qrow = qb + ((bh << 10) + t0 + (w << 4) + lr) * 64;
  short8 qf0 = *(const short8*)&qrow[lg * 8];
  short8 qf1 = *(const short8*)&qrow[32 + lg * 8];
  const u16* kbase = kb + (size_t)(bh << 11) * 64;
  const u16* vbase = vtb + (size_t)(bh << 6) * 2048;
  f32x4 acc[4] = {};
  float m_r[4] = {-1e30f, -1e30f, -1e30f, -1e30f};
  float l_r[4] = {0.f, 0.f, 0.f, 0.f};
  const int n1 = (t0 >> 6) + 1;           // tiles in the "past" range
  for (int ti = 0; ti < 17; ti++) {
    const int s0 = (ti < n1) ? (ti << 6) : (t0 + 1024 + ((ti - n1) << 6));
    __syncthreads();
#pragma unroll
    for (int it = 0; it < 2; it++) {
      int idx = tid + it * 256;
      int row = idx >> 3, c = (idx & 7) << 3;
      *(uint4*)&Kt[row * 72 + c] = *(const uint4*)&kbase[(s0 + row) * 64 + c];
      *(uint4*)&Vt[row * 72 + c] = *(const uint4*)&vbase[row * 2048 + s0 + c];
    }
    __syncthreads();
    float S[4][4];
#pragma unroll
    for (int c = 0; c < 4; c++) {
      f32x4 sc = {};
      short8 kf0 = *(const short8*)&Kt[(c * 16 + lr) * 72 + lg * 8];
      short8 kf1 = *(const short8*)&Kt[(c * 16 + lr) * 72 + 32 + lg * 8];
      sc = __builtin_amdgcn_mfma_f32_16x16x32_bf16(qf0, kf0, sc, 0, 0, 0);
      sc = __builtin_amdgcn_mfma_f32_16x16x32_bf16(qf1, kf1, sc, 0, 0, 0);
      int j = s0 + c * 16 + lr;
#pragma unroll
      for (int r = 0; r < 4; r++) {
        int i = t0 + (w << 4) + lg * 4 + r;
        S[c][r] = ((j < i) || (j > i + 1024)) ? sc[r] : -1e30f;
      }
    }
    float pv[4][4];
#pragma unroll
    for (int r = 0; r < 4; r++) {
      float tm = fmaxf(fmaxf(S[0][r], S[1][r]), fmaxf(S[2][r], S[3][r]));
      tm = fmaxf(tm, __shfl_xor(tm, 1));
      tm = fmaxf(tm, __shfl_xor(tm, 2));
      tm = fmaxf(tm, __shfl_xor(tm, 4));
      tm = fmaxf(tm, __shfl_xor(tm, 8));
      float mn = fmaxf(m_r[r], tm);
      float sc2 = __expf(m_r[r] - mn);
      m_r[r] = mn;
      float rs = 0.f;
#pragma unroll
      for (int c = 0; c < 4; c++) {
        float p = (S[c][r] > -1e29f) ? __expf(S[c][r] - mn) : 0.f;
        pv[c][r] = p;
        rs += p;
      }
      rs += __shfl_xor(rs, 1);
      rs += __shfl_xor(rs, 2);
      rs += __shfl_xor(rs, 4);
      rs += __shfl_xor(rs, 8);
      l_r[r] = l_r[r] * sc2 + rs;
      acc[0][r] *= sc2; acc[1][r] *= sc2; acc[2][r] *= sc2; acc[3][r] *= sc2;
    }
#pragma unroll
    for (int c = 0; c < 4; c++)
#pragma unroll
      for (int r = 0; r < 4; r++)
        Pt[w][(lg * 4 + r) * 72 + c * 16 + lr] = f2b(pv[c][r]);
    __syncthreads();   // orders P write -> P read (and keeps waves in lockstep)
    short8 pf0 = *(const short8*)&Pt[w][lr * 72 + lg * 8];
    short8 pf1 = *(const short8*)&Pt[w][lr * 72 + 32 + lg * 8];
#pragma unroll
    for (int dd = 0; dd < 4; dd++) {
      short8 vf0 = *(const short8*)&Vt[(dd * 16 + lr) * 72 + lg * 8];
      short8 vf1 = *(const short8*)&Vt[(dd * 16 + lr) * 72 + 32 + lg * 8];
      acc[dd] = __builtin_amdgcn_mfma_f32_16x16x32_bf16(pf0, vf0, acc[dd], 0, 0, 0);
      acc[dd] = __builtin_amdgcn_mfma_f32_16x16x32_bf16(pf1, vf1, acc[dd], 0, 0, 0);
    }
  }
  float inv[4];
#pragma unroll
  for (int r = 0; r < 4; r++) inv[r] = 1.f / l_r[r];
  const int trow = t0 + (w << 4) + lg * 4;
#pragma unroll
  for (int dd = 0; dd < 4; dd++)
#pragma unroll
    for (int r = 0; r < 4; r++)
      attn_bf[((trow + r) * 4 + b) * 1024 + h * 64 + dd * 16 + lr] = f2b(acc[dd][r] * inv[r]);
#pragma unroll
  for (int r = 0; r < 4; r++)
    if (lr == r) {
      st_m[(bh << 10) + trow + r] = m_r[r];
      st_il[(bh << 10) + trow + r] = inv[r];
    }
}

// ---------------------------------------------------------------------------
// avg_weights[b,t,s] = (1/H) sum_h exp(q.k - m[b,h,t]) * il[b,h,t] (masked -> 0)
// 1 block = (b, 64 t-rows, 128 s-cols); fully-masked blocks write zeros.
// ---------------------------------------------------------------------------
__global__ __launch_bounds__(256) void attn_avg(const u16* __restrict__ qb,
                                                const u16* __restrict__ kb,
                                                const float* __restrict__ st_m,
                                                const float* __restrict__ st_il,
                                                float* __restrict__ avg) {
  const int blk = blockIdx.x;
  const int s0 = (blk & 15) << 7;
  const int t0 = ((blk >> 4) & 15) << 6;
  const int b = blk >> 8;
  const int tid = threadIdx.x, lane = tid & 63, w = tid >> 6;
  const int lr = lane & 15, lg = lane >> 4;
  const int trow = t0 + (w << 4) + lg * 4;
  float* obase = avg + (size_t)b * (1024 * 2048);
  if ((s0 > t0 + 62) && (s0 + 127 < t0 + 1025)) {   // fully masked tile
#pragma unroll
    for (int c = 0; c < 8; c++)
#pragma unroll
      for (int r = 0; r < 4; r++)
        obase[(trow + r) * 2048 + s0 + c * 16 + lr] = 0.f;
    return;
  }
  float accv[8][4] = {};
  for (int h = 0; h < 16; h++) {
    const int bh = b * 16 + h;
    const u16* qrow = qb + ((bh << 10) + t0 + (w << 4) + lr) * 64;
    short8 qf0 = *(const short8*)&qrow[lg * 8];
    short8 qf1 = *(const short8*)&qrow[32 + lg * 8];
    float mh[4], ih[4];
#pragma unroll
    for (int r = 0; r < 4; r++) {
      mh[r] = st_m[(bh << 10) + trow + r];
      ih[r] = st_il[(bh << 10) + trow + r];
    }
    const u16* krow = kb + (size_t)((bh << 11) + s0) * 64;
#pragma unroll
    for (int c = 0; c < 8; c++) {
      f32x4 sc = {};
      short8 kf0 = *(const short8*)&krow[(c * 16 + lr) * 64 + lg * 8];
      short8 kf1 = *(const short8*)&krow[(c * 16 + lr) * 64 + 32 + lg * 8];
      sc = __builtin_amdgcn_mfma_f32_16x16x32_bf16(qf0, kf0, sc, 0, 0, 0);
      sc = __builtin_amdgcn_mfma_f32_16x16x32_bf16(qf1, kf1, sc, 0, 0, 0);
      int j = s0 + c * 16 + lr;
#pragma unroll
      for (int r = 0; r < 4; r++) {
        int i = t0 + (w << 4) + lg * 4 + r;
        if ((j < i) || (j > i + 1024))
          accv[c][r] += __expf(sc[r] - mh[r]) * ih[r];
      }
    }
  }
#pragma unroll
  for (int c = 0; c < 8; c++)
#pragma unroll
    for (int r = 0; r < 4; r++)
      obase[(trow + r) * 2048 + s0 + c * 16 + lr] = accv[c][r] * 0.0625f;
}

// ---------------------------------------------------------------------------
extern "C" void kernel_launch(void* const* d_in, const int* in_sizes, int n_in,
                              void* d_out, int out_size, void* d_ws, size_t ws_size,
                              hipStream_t stream) {
  const float* fwd   = (const float*)d_in[0];
  const float* bwd   = (const float*)d_in[1];
  const float* w_in  = (const float*)d_in[2];   // (3E, E)
  const float* b_in  = (const float*)d_in[3];   // (3E,)
  const float* w_out = (const float*)d_in[4];   // (E, E)
  const float* b_out = (const float*)d_in[5];   // (E,)

  char* ws = (char*)d_ws;
  u16*  q_in_bf = (u16*)(ws);                    //  8,388,608 B  (4096 x 1024)
  u16*  kv_bf   = (u16*)(ws + 8388608);          // 16,777,216 B  (8192 x 1024)
  u16*  w_bf    = (u16*)(ws + 25165824);         //  6,291,456 B  (3E x E)
  u16*  wo_bf   = (u16*)(ws + 31457280);         //  2,097,152 B  (E x E)
  u16*  q_bf    = (u16*)(ws + 33554432);         //  8,388,608 B  (B,H,T,Dh)
  u16*  k_bf    = (u16*)(ws + 41943040);         // 16,777,216 B  (B,H,S,Dh)
  u16*  vt_bf   = (u16*)(ws + 58720256);         // 16,777,216 B  (B,H,Dh,S)
  u16*  attn_bf = (u16*)(ws + 75497472);         //  8,388,608 B  (T,B,E)
  float* st_m   = (float*)(ws + 83886080);       //    262,144 B  (B,H,T)
  float* st_il  = (float*)(ws + 84148224);       //    262,144 B  (B,H,T)
  // total ws use: 84,410,368 B

  float* out_attn = (float*)d_out;               // (T,B,E) f32
  float* out_avg  = (float*)d_out + 4194304;     // (B,T,S) f32

  prep_qin<<<4096, 256, 0, stream>>>(fwd, bwd, q_in_bf);
  cast_bf16<<<4096, 256, 0, stream>>>(fwd, kv_bf);
  cast_bf16<<<4096, 256, 0, stream>>>(bwd, kv_bf + 4194304);
  cast_bf16<<<3072, 256, 0, stream>>>(w_in, w_bf);
  cast_bf16<<<1024, 256, 0, stream>>>(w_out, wo_bf);

  gemm_bt<0><<<dim3(32, 8), 256, 0, stream>>>(q_in_bf, w_bf, b_in, (void*)q_bf);
  gemm_bt<1><<<dim3(64, 8), 256, 0, stream>>>(kv_bf, w_bf + 1048576, b_in + 1024, (void*)k_bf);
  gemm_bt<2><<<dim3(64, 8), 256, 0, stream>>>(kv_bf, w_bf + 2097152, b_in + 2048, (void*)vt_bf);

  attn_fwd<<<1024, 256, 0, stream>>>(q_bf, k_bf, vt_bf, attn_bf, st_m, st_il);

  gemm_bt<3><<<dim3(32, 8), 256, 0, stream>>>(attn_bf, wo_bf, b_out, (void*)out_attn);

  attn_avg<<<1024, 256, 0, stream>>>(q_bf, k_bf, st_m, st_il, out_avg);
}

// Round 2
// 254.522 us; speedup vs baseline: 1.3242x; 1.3242x over previous
//
#include <hip/hip_runtime.h>

typedef unsigned short u16;
typedef __attribute__((ext_vector_type(8))) short short8;
typedef __attribute__((ext_vector_type(4))) float f32x4;

// f32 -> bf16 round-to-nearest-even (finite values only)
__device__ __forceinline__ u16 f2b(float f) {
  unsigned u = __float_as_uint(f);
  unsigned r = (u + 0x7FFFu + ((u >> 16) & 1u)) >> 16;
  return (u16)r;
}

// async global->LDS, 16B per lane. LDS dest must be wave-uniform base + lane*16
// (we pass per-lane ptrs that satisfy exactly that layout).
__device__ __forceinline__ void gload16(const u16* g, u16* l) {
  __builtin_amdgcn_global_load_lds((const __attribute__((address_space(1))) void*)g,
                                   (__attribute__((address_space(3))) void*)l, 16, 0, 0);
}

// ---------------------------------------------------------------------------
// prep: q_in[t,b,:] = (t>0 ? fwd[t-1,b,:] : 0) + (t<T-1 ? bwd[t+1,b,:] : 0), bf16
// ---------------------------------------------------------------------------
__global__ __launch_bounds__(256) void prep_qin(const float* __restrict__ fwd,
                                                const float* __restrict__ bwd,
                                                u16* __restrict__ qin) {
  int gid = blockIdx.x * 256 + threadIdx.x;
  int n = gid >> 8;
  int e4 = (gid & 255) << 2;
  int t = n >> 2, b = n & 3;
  float4 acc = make_float4(0.f, 0.f, 0.f, 0.f);
  if (t > 0) {
    float4 v = *(const float4*)(fwd + (((t - 1) * 4 + b) << 10) + e4);
    acc.x += v.x; acc.y += v.y; acc.z += v.z; acc.w += v.w;
  }
  if (t < 1023) {
    float4 v = *(const float4*)(bwd + (((t + 1) * 4 + b) << 10) + e4);
    acc.x += v.x; acc.y += v.y; acc.z += v.z; acc.w += v.w;
  }
  ushort4 o; o.x = f2b(acc.x); o.y = f2b(acc.y); o.z = f2b(acc.z); o.w = f2b(acc.w);
  *(ushort4*)(qin + (n << 10) + e4) = o;
}

__global__ __launch_bounds__(256) void cast_bf16(const float* __restrict__ src,
                                                 u16* __restrict__ dst) {
  int gid = blockIdx.x * 256 + threadIdx.x;
  float4 v = *(const float4*)(src + (gid << 2));
  ushort4 o; o.x = f2b(v.x); o.y = f2b(v.y); o.z = f2b(v.z); o.w = f2b(v.w);
  *(ushort4*)(dst + (gid << 2)) = o;
}

// ---------------------------------------------------------------------------
// GEMM (m97 structure): C[m,n] = sum_k A[m,k]*W[n,k] + bias[n]  (bf16, K=N=1024)
// 128x128 tile, 4 waves (2x2 of 64x64), linear LDS + global_load_lds width 16.
// ---------------------------------------------------------------------------
template <int MODE>
__global__ __launch_bounds__(256) void gemm_bt(const u16* __restrict__ A,
                                               const u16* __restrict__ W,
                                               const float* __restrict__ bias,
                                               void* __restrict__ outp) {
  __shared__ u16 At[128 * 64];
  __shared__ u16 Wt[128 * 64];
  const int m0 = blockIdx.x << 7, n0 = blockIdx.y << 7;
  const int tid = threadIdx.x;
  const int lane = tid & 63, wid = tid >> 6;
  const int wm = (wid >> 1) << 6, wn = (wid & 1) << 6;
  const int lr = lane & 15, lg = lane >> 4;
  const int srow = lane >> 3, scol = (lane & 7) << 3;   // staging: 8 rows x 8 chunks / wave
  f32x4 acc[4][4] = {};
  for (int k0 = 0; k0 < 1024; k0 += 64) {
    __syncthreads();   // previous tile's reads done before overwrite
#pragma unroll
    for (int it = 0; it < 4; it++) {
      int row = (it * 4 + wid) * 8 + srow;
      gload16(&A[(m0 + row) * 1024 + k0 + scol], &At[row * 64 + scol]);
      gload16(&W[(n0 + row) * 1024 + k0 + scol], &Wt[row * 64 + scol]);
    }
    __syncthreads();   // drain (compiler emits vmcnt(0) before barrier)
#pragma unroll
    for (int kk = 0; kk < 64; kk += 32) {
      short8 af[4], bf[4];
#pragma unroll
      for (int i = 0; i < 4; i++) {
        af[i] = *(const short8*)&At[(wm + i * 16 + lr) * 64 + kk + lg * 8];
        bf[i] = *(const short8*)&Wt[(wn + i * 16 + lr) * 64 + kk + lg * 8];
      }
#pragma unroll
      for (int i = 0; i < 4; i++)
#pragma unroll
        for (int j = 0; j < 4; j++)
          acc[i][j] = __builtin_amdgcn_mfma_f32_16x16x32_bf16(af[i], bf[j], acc[i][j], 0, 0, 0);
    }
  }
  // epilogue: D row = lg*4+r, col = lr
#pragma unroll
  for (int i = 0; i < 4; i++) {
#pragma unroll
    for (int j = 0; j < 4; j++) {
      int n = n0 + wn + j * 16 + lr;
      float bv = bias[n];
#pragma unroll
      for (int r = 0; r < 4; r++) {
        int m = m0 + wm + i * 16 + lg * 4 + r;
        float v = acc[i][j][r] + bv;
        if (MODE == 3) {
          ((float*)outp)[m * 1024 + n] = v;
        } else {
          int tb = m & 3, ts = m >> 2, h = n >> 6, d = n & 63;
          u16* ob = (u16*)outp;
          if (MODE == 0) ob[((tb * 16 + h) * 1024 + ts) * 64 + d] = f2b(v);
          if (MODE == 1) ob[((tb * 16 + h) * 2048 + ts) * 64 + d] = f2b(v);
          if (MODE == 2) ob[((tb * 16 + h) * 64 + d) * 2048 + ts] = f2b(v);
        }
      }
    }
  }
}

// ---------------------------------------------------------------------------
// Flash attention: 1 block = (b, h, 64 q-rows). 4 waves x 16-row strips.
// K/V staged via global_load_lds with pre-swizzled source (chunk ^= row&7),
// reads XOR-swizzled -> conflict-free ds_read_b128.
// ---------------------------------------------------------------------------
__global__ __launch_bounds__(256) void attn_fwd(const u16* __restrict__ qb,
                                                const u16* __restrict__ kb,
                                                const u16* __restrict__ vtb,
                                                u16* __restrict__ attn_bf,
                                                float* __restrict__ st_m,
                                                float* __restrict__ st_il) {
  __shared__ u16 Kt[64 * 64];
  __shared__ u16 Vt[64 * 64];
  __shared__ u16 Pt[4][16 * 72];
  const int blk = blockIdx.x;
  const int t0 = (blk & 15) << 6;
  const int h = (blk >> 4) & 15;
  const int b = blk >> 8;
  const int tid = threadIdx.x, lane = tid & 63, w = tid >> 6;
  const int lr = lane & 15, lg = lane >> 4;
  const int bh = b * 16 + h;
  const int sw0 = ((lg ^ (lr & 7)) << 3);   // read-side swizzle (row&7 == lr&7)
  const int sw1 = sw0 ^ 32;
  const u16* qrow = qb + ((bh << 10) + t0 + (w << 4) + lr) * 64;
  short8 qf0 = *(const short8*)&qrow[lg * 8];
  short8 qf1 = *(const short8*)&qrow[32 + lg * 8];
  const u16* kbase = kb + (size_t)(bh << 11) * 64;
  const u16* vbase = vtb + (size_t)(bh << 6) * 2048;
  f32x4 acc[4] = {};
  float m_r[4] = {-1e30f, -1e30f, -1e30f, -1e30f};
  float l_r[4] = {0.f, 0.f, 0.f, 0.f};
  const int n1 = (t0 >> 6) + 1;
  // staging geometry: chunk ci covers 8 rows; lane -> row ci*8+(lane>>3), 16B slot lane&7
  const int grow = lane >> 3, gcol = (lane & 7) << 3;
  for (int ti = 0; ti < 17; ti++) {
    const int s0 = (ti < n1) ? (ti << 6) : (t0 + 1024 + ((ti - n1) << 6));
    __syncthreads();
#pragma unroll
    for (int it = 0; it < 2; it++) {
      int row = (it * 4 + w) * 8 + grow;
      int swc = (((lane & 7) ^ (row & 7)) << 3);   // pre-swizzled source chunk
      gload16(&kbase[(size_t)(s0 + row) * 64 + swc], &Kt[row * 64 + gcol]);
      gload16(&vbase[(size_t)row * 2048 + s0 + swc], &Vt[row * 64 + gcol]);
    }
    __syncthreads();
    float S[4][4];
#pragma unroll
    for (int c = 0; c < 4; c++) {
      f32x4 sc = {};
      short8 kf0 = *(const short8*)&Kt[(c * 16 + lr) * 64 + sw0];
      short8 kf1 = *(const short8*)&Kt[(c * 16 + lr) * 64 + sw1];
      sc = __builtin_amdgcn_mfma_f32_16x16x32_bf16(qf0, kf0, sc, 0, 0, 0);
      sc = __builtin_amdgcn_mfma_f32_16x16x32_bf16(qf1, kf1, sc, 0, 0, 0);
      int j = s0 + c * 16 + lr;
#pragma unroll
      for (int r = 0; r < 4; r++) {
        int i = t0 + (w << 4) + lg * 4 + r;
        S[c][r] = ((j < i) || (j > i + 1024)) ? sc[r] : -1e30f;
      }
    }
    float pv[4][4];
#pragma unroll
    for (int r = 0; r < 4; r++) {
      float tm = fmaxf(fmaxf(S[0][r], S[1][r]), fmaxf(S[2][r], S[3][r]));
      tm = fmaxf(tm, __shfl_xor(tm, 1));
      tm = fmaxf(tm, __shfl_xor(tm, 2));
      tm = fmaxf(tm, __shfl_xor(tm, 4));
      tm = fmaxf(tm, __shfl_xor(tm, 8));
      float mn = fmaxf(m_r[r], tm);
      float sc2 = __expf(m_r[r] - mn);
      m_r[r] = mn;
      float rs = 0.f;
#pragma unroll
      for (int c = 0; c < 4; c++) {
        float p = (S[c][r] > -1e29f) ? __expf(S[c][r] - mn) : 0.f;
        pv[c][r] = p;
        rs += p;
      }
      rs += __shfl_xor(rs, 1);
      rs += __shfl_xor(rs, 2);
      rs += __shfl_xor(rs, 4);
      rs += __shfl_xor(rs, 8);
      l_r[r] = l_r[r] * sc2 + rs;
      acc[0][r] *= sc2; acc[1][r] *= sc2; acc[2][r] *= sc2; acc[3][r] *= sc2;
    }
#pragma unroll
    for (int c = 0; c < 4; c++)
#pragma unroll
      for (int r = 0; r < 4; r++)
        Pt[w][(lg * 4 + r) * 72 + c * 16 + lr] = f2b(pv[c][r]);
    __syncthreads();   // P write -> P read; also keeps Kt/Vt live until PV done
    short8 pf0 = *(const short8*)&Pt[w][lr * 72 + lg * 8];
    short8 pf1 = *(const short8*)&Pt[w][lr * 72 + 32 + lg * 8];
#pragma unroll
    for (int dd = 0; dd < 4; dd++) {
      short8 vf0 = *(const short8*)&Vt[(dd * 16 + lr) * 64 + sw0];
      short8 vf1 = *(const short8*)&Vt[(dd * 16 + lr) * 64 + sw1];
      acc[dd] = __builtin_amdgcn_mfma_f32_16x16x32_bf16(pf0, vf0, acc[dd], 0, 0, 0);
      acc[dd] = __builtin_amdgcn_mfma_f32_16x16x32_bf16(pf1, vf1, acc[dd], 0, 0, 0);
    }
  }
  float inv[4];
#pragma unroll
  for (int r = 0; r < 4; r++) inv[r] = 1.f / l_r[r];
  const int trow = t0 + (w << 4) + lg * 4;
#pragma unroll
  for (int dd = 0; dd < 4; dd++)
#pragma unroll
    for (int r = 0; r < 4; r++)
      attn_bf[((trow + r) * 4 + b) * 1024 + h * 64 + dd * 16 + lr] = f2b(acc[dd][r] * inv[r]);
#pragma unroll
  for (int r = 0; r < 4; r++)
    if (lr == r) {
      st_m[(bh << 10) + trow + r] = m_r[r];
      st_il[(bh << 10) + trow + r] = inv[r];
    }
}

// ---------------------------------------------------------------------------
// avg_weights[b,t,s] = (1/H) sum_h exp(q.k - m[b,h,t]) * il[b,h,t] (masked -> 0)
// 1 block = (b, 64 t-rows, 128 s-cols). K staged in LDS per head (gload_lds,
// swizzled); softmax stats staged once per block.
// ---------------------------------------------------------------------------
__global__ __launch_bounds__(256) void attn_avg(const u16* __restrict__ qb,
                                                const u16* __restrict__ kb,
                                                const float* __restrict__ st_m,
                                                const float* __restrict__ st_il,
                                                float* __restrict__ avg) {
  __shared__ u16 Kt[128 * 64];       // 16KB
  __shared__ float Sm[16][64];       // 4KB
  __shared__ float Si[16][64];       // 4KB
  const int blk = blockIdx.x;
  const int s0 = (blk & 15) << 7;
  const int t0 = ((blk >> 4) & 15) << 6;
  const int b = blk >> 8;
  const int tid = threadIdx.x, lane = tid & 63, w = tid >> 6;
  const int lr = lane & 15, lg = lane >> 4;
  const int trow = t0 + (w << 4) + lg * 4;
  float* obase = avg + (size_t)b * (1024 * 2048);
  if ((s0 > t0 + 62) && (s0 + 127 < t0 + 1025)) {   // fully masked tile
#pragma unroll
    for (int c = 0; c < 8; c++)
#pragma unroll
      for (int r = 0; r < 4; r++)
        obase[(trow + r) * 2048 + s0 + c * 16 + lr] = 0.f;
    return;
  }
  // stage stats for this block's 64 t-rows, all 16 heads
  for (int i = tid; i < 1024; i += 256) {
    int hh = i >> 6, tt = i & 63;
    Sm[hh][tt] = st_m[(((b << 4) + hh) << 10) + t0 + tt];
    Si[hh][tt] = st_il[(((b << 4) + hh) << 10) + t0 + tt];
  }
  const int sw0 = ((lg ^ (lr & 7)) << 3);
  const int sw1 = sw0 ^ 32;
  const int grow = lane >> 3, gcol = (lane & 7) << 3;
  const int srr = (w << 4) + lg * 4;     // stat row within block
  float accv[8][4] = {};
  for (int h = 0; h < 16; h++) {
    const int bh = (b << 4) + h;
    __syncthreads();   // Kt consumed (h>0); stats visible (h==0)
#pragma unroll
    for (int it = 0; it < 4; it++) {
      int row = (it * 4 + w) * 8 + grow;
      int swc = (((lane & 7) ^ (row & 7)) << 3);
      gload16(&kb[(size_t)((bh << 11) + s0 + row) * 64 + swc], &Kt[row * 64 + gcol]);
    }
    const u16* qrow = qb + ((bh << 10) + t0 + (w << 4) + lr) * 64;
    short8 qf0 = *(const short8*)&qrow[lg * 8];
    short8 qf1 = *(const short8*)&qrow[32 + lg * 8];
    __syncthreads();   // drain staging
    float mh[4], ih[4];
#pragma unroll
    for (int r = 0; r < 4; r++) {
      mh[r] = Sm[h][srr + r];
      ih[r] = Si[h][srr + r];
    }
#pragma unroll
    for (int c = 0; c < 8; c++) {
      f32x4 sc = {};
      short8 kf0 = *(const short8*)&Kt[(c * 16 + lr) * 64 + sw0];
      short8 kf1 = *(const short8*)&Kt[(c * 16 + lr) * 64 + sw1];
      sc = __builtin_amdgcn_mfma_f32_16x16x32_bf16(qf0, kf0, sc, 0, 0, 0);
      sc = __builtin_amdgcn_mfma_f32_16x16x32_bf16(qf1, kf1, sc, 0, 0, 0);
      int j = s0 + c * 16 + lr;
#pragma unroll
      for (int r = 0; r < 4; r++) {
        int i = t0 + (w << 4) + lg * 4 + r;
        if ((j < i) || (j > i + 1024))
          accv[c][r] += __expf(sc[r] - mh[r]) * ih[r];
      }
    }
  }
#pragma unroll
  for (int c = 0; c < 8; c++)
#pragma unroll
    for (int r = 0; r < 4; r++)
      obase[(trow + r) * 2048 + s0 + c * 16 + lr] = accv[c][r] * 0.0625f;
}

// ---------------------------------------------------------------------------
extern "C" void kernel_launch(void* const* d_in, const int* in_sizes, int n_in,
                              void* d_out, int out_size, void* d_ws, size_t ws_size,
                              hipStream_t stream) {
  const float* fwd   = (const float*)d_in[0];
  const float* bwd   = (const float*)d_in[1];
  const float* w_in  = (const float*)d_in[2];   // (3E, E)
  const float* b_in  = (const float*)d_in[3];   // (3E,)
  const float* w_out = (const float*)d_in[4];   // (E, E)
  const float* b_out = (const float*)d_in[5];   // (E,)

  char* ws = (char*)d_ws;
  u16*  q_in_bf = (u16*)(ws);                    //  8,388,608 B  (4096 x 1024)
  u16*  kv_bf   = (u16*)(ws + 8388608);          // 16,777,216 B  (8192 x 1024)
  u16*  w_bf    = (u16*)(ws + 25165824);         //  6,291,456 B  (3E x E)
  u16*  wo_bf   = (u16*)(ws + 31457280);         //  2,097,152 B  (E x E)
  u16*  q_bf    = (u16*)(ws + 33554432);         //  8,388,608 B  (B,H,T,Dh)
  u16*  k_bf    = (u16*)(ws + 41943040);         // 16,777,216 B  (B,H,S,Dh)
  u16*  vt_bf   = (u16*)(ws + 58720256);         // 16,777,216 B  (B,H,Dh,S)
  u16*  attn_bf = (u16*)(ws + 75497472);         //  8,388,608 B  (T,B,E)
  float* st_m   = (float*)(ws + 83886080);       //    262,144 B  (B,H,T)
  float* st_il  = (float*)(ws + 84148224);       //    262,144 B  (B,H,T)

  float* out_attn = (float*)d_out;               // (T,B,E) f32
  float* out_avg  = (float*)d_out + 4194304;     // (B,T,S) f32

  prep_qin<<<4096, 256, 0, stream>>>(fwd, bwd, q_in_bf);
  cast_bf16<<<4096, 256, 0, stream>>>(fwd, kv_bf);
  cast_bf16<<<4096, 256, 0, stream>>>(bwd, kv_bf + 4194304);
  cast_bf16<<<3072, 256, 0, stream>>>(w_in, w_bf);
  cast_bf16<<<1024, 256, 0, stream>>>(w_out, wo_bf);

  gemm_bt<0><<<dim3(32, 8), 256, 0, stream>>>(q_in_bf, w_bf, b_in, (void*)q_bf);
  gemm_bt<1><<<dim3(64, 8), 256, 0, stream>>>(kv_bf, w_bf + 1048576, b_in + 1024, (void*)k_bf);
  gemm_bt<2><<<dim3(64, 8), 256, 0, stream>>>(kv_bf, w_bf + 2097152, b_in + 2048, (void*)vt_bf);

  attn_fwd<<<1024, 256, 0, stream>>>(q_bf, k_bf, vt_bf, attn_bf, st_m, st_il);

  gemm_bt<3><<<dim3(32, 8), 256, 0, stream>>>(attn_bf, wo_bf, b_out, (void*)out_attn);

  attn_avg<<<1024, 256, 0, stream>>>(q_bf, k_bf, st_m, st_il, out_avg);
}